// Round 5
// baseline (309.352 us; speedup 1.0000x reference)
//
#include <hip/hip_runtime.h>
#include <hip/hip_bf16.h>

// Problem constants (from reference)
#define NW   8192
#define NS   8192
#define FD   1024
#define EMB  128
#define QN   1024
#define NC   80

typedef unsigned short ushort_t;
typedef unsigned int   uint_t;
typedef __attribute__((ext_vector_type(8))) short short8;
typedef __attribute__((ext_vector_type(4))) float f32x4;

// ---------- workspace layout (element offsets, 4B units) ----------
#define OFF_Q      0u           // float [NW*EMB]
#define OFF_K      1048576u     // float [NS*EMB]
#define OFF_TABLE  2097152u     // int   [NC*8192] — aliases Wt (enc runs before table_k)
#define OFF_WTQ    2097152u     // ushort[1024*128] (aliases table)
#define OFF_WTK    2129920u     // ushort[1024*128]
#define OFF_HIST   2752512u     // int   [128]
#define OFF_RANK   2752640u     // int   [NW]
#define OFF_OCC    2760832u     // int   [NS]
#define OFF_IDX    2769024u     // int   [NW]
#define OFF_BHS    2785408u     // int   [32*NC]
#define OFF_BHW    2787968u     // int   [32*NC]
#define OFF_ACC    2790528u     // float [2] : {sum_ce, valid_count}
#define OFF_QT     2790532u     // ushort[1024*128] (Qt: queue^T bf16)

__device__ __forceinline__ ushort_t f2bf(float f) {   // fp32 -> bf16 RNE
    uint_t u = __float_as_uint(f);
    u = (u + 0x7fffu + ((u >> 16) & 1u)) >> 16;
    return (ushort_t)u;
}
__device__ __forceinline__ uint_t pack2(float a, float b) {
    return (uint_t)f2bf(a) | ((uint_t)f2bf(b) << 16);
}

// ---------------- convert+transpose: W -> Wt (tiled bf16), queue -> Qt (bf16) ----------------
// z=0: Wq[1024][128] -> Wtq[kb][n][kk]  (kb=k>>5, kk=k&31)
// z=1: Wk -> Wtk same;  z=2: queue[128][1024] -> Qt[n=1024][k=128]
// Also zeroes accum (block 0,0).
__global__ __launch_bounds__(256) void cvt_k(const float* __restrict__ Wq,
                                             const float* __restrict__ Wk,
                                             const float* __restrict__ queue,
                                             ushort_t* __restrict__ Wtq,
                                             ushort_t* __restrict__ Wtk,
                                             ushort_t* __restrict__ Qt,
                                             float* __restrict__ accum) {
    __shared__ float tile[32][33];
    int z = blockIdx.y, flat = blockIdx.x;
    int t = threadIdx.x;
    if (z == 0 && flat == 0 && t < 2) accum[t] = 0.0f;
    const float* in; ushort_t* out; int r0, c0, C;
    if (z < 2) { in = z ? Wk : Wq; out = z ? Wtk : Wtq; C = 128;
                 r0 = (flat >> 2) * 32; c0 = (flat & 3) * 32; }
    else       { in = queue; out = Qt; C = 1024;
                 r0 = (flat & 3) * 32; c0 = (flat >> 2) * 32; }
    int i = t >> 3, j0 = (t & 7) * 4;
    float4 v = *(const float4*)(in + (size_t)(r0 + i) * C + c0 + j0);
    tile[i][j0] = v.x; tile[i][j0 + 1] = v.y; tile[i][j0 + 2] = v.z; tile[i][j0 + 3] = v.w;
    __syncthreads();
    uint2 pk;
    pk.x = pack2(tile[j0][i], tile[j0 + 1][i]);
    pk.y = pack2(tile[j0 + 2][i], tile[j0 + 3][i]);
    size_t oaddr;
    if (z < 2) oaddr = ((size_t)(r0 >> 5) * 128 + (c0 + i)) * 32 + j0;   // tiled [kb][n][kk]
    else       oaddr = (size_t)(c0 + i) * 128 + (r0 + j0);               // plain [n][k]
    *(uint2*)(out + oaddr) = pk;
}

// ---------------- encoder GEMM (MFMA, zero-LDS, zero-barrier) ----------------
// grid 256: bx>>7 selects encoder, bx&127 = 64-row tile. 4 waves, each 16 rows x 128 cols.
// A fp32 rows read once, converted in registers; Wt fragments direct from global (L2-hot).
__global__ __launch_bounds__(256) void enc_mfma_k(const float* __restrict__ A0,
                                                  const float* __restrict__ A1,
                                                  const ushort_t* __restrict__ Wt0,
                                                  const ushort_t* __restrict__ Wt1,
                                                  const float* __restrict__ b0,
                                                  const float* __restrict__ b1,
                                                  float* __restrict__ out0,
                                                  float* __restrict__ out1) {
    int bx = blockIdx.x;
    int which = bx >> 7;
    int mtile = bx & 127;
    const float*    A    = which ? A1 : A0;
    const ushort_t* Wt   = which ? Wt1 : Wt0;
    const float*    bias = which ? b1 : b0;
    float*          out  = which ? out1 : out0;

    int t = threadIdx.x;
    int wv = t >> 6, ln = t & 63;
    int lane15 = ln & 15, kg = ln >> 4;
    int row0 = mtile * 64 + wv * 16;

    const float* arow = A + (size_t)(row0 + lane15) * FD + kg * 8;
    const ushort_t* wbase = Wt + lane15 * 32 + kg * 8;

    f32x4 acc[8];
#pragma unroll
    for (int nt = 0; nt < 8; nt++) acc[nt] = (f32x4){0.f, 0.f, 0.f, 0.f};

    float4 pa[2][2]; uint4 pb[2][8];
    pa[0][0] = *(const float4*)(arow);
    pa[0][1] = *(const float4*)(arow + 4);
#pragma unroll
    for (int nt = 0; nt < 8; nt++) pb[0][nt] = *(const uint4*)(wbase + nt * 512);

    for (int kb = 0; kb < 32; kb++) {
        int cur = kb & 1, nxt = cur ^ 1;
        if (kb < 31) {
            const float* ap = arow + (kb + 1) * 32;
            pa[nxt][0] = *(const float4*)ap;
            pa[nxt][1] = *(const float4*)(ap + 4);
            const ushort_t* wp = wbase + (size_t)(kb + 1) * 4096;
#pragma unroll
            for (int nt = 0; nt < 8; nt++) pb[nxt][nt] = *(const uint4*)(wp + nt * 512);
        }
        uint4 pk;
        pk.x = pack2(pa[cur][0].x, pa[cur][0].y);
        pk.y = pack2(pa[cur][0].z, pa[cur][0].w);
        pk.z = pack2(pa[cur][1].x, pa[cur][1].y);
        pk.w = pack2(pa[cur][1].z, pa[cur][1].w);
        short8 af = __builtin_bit_cast(short8, pk);
#pragma unroll
        for (int nt = 0; nt < 8; nt++) {
            short8 bf = __builtin_bit_cast(short8, pb[cur][nt]);
            acc[nt] = __builtin_amdgcn_mfma_f32_16x16x32_bf16(af, bf, acc[nt], 0, 0, 0);
        }
    }

    // epilogue: C[row][col], row-within-16 = kg*4+j, col = nt*16+lane15
#pragma unroll
    for (int nt = 0; nt < 8; nt++) {
        int col = nt * 16 + lane15;
        float bv = bias[col];
        int rbase = row0 + kg * 4;
#pragma unroll
        for (int j = 0; j < 4; j++)
            out[(size_t)(rbase + j) * EMB + col] = acc[nt][j] + bv;
    }
}

// ---------------- per-block class histograms for both label arrays ----------------
// grid 64: bx>>5 selects array (0=s,1=w), bx&31 = 256-elem chunk.
__global__ __launch_bounds__(256) void bh_k(const int* __restrict__ s, const int* __restrict__ w,
                                            int* __restrict__ bhs, int* __restrict__ bhw) {
    __shared__ int h[NC];
    int bx = blockIdx.x, z = bx >> 5, cb = bx & 31;
    const int* lab = z ? w : s;
    int* bh = z ? bhw : bhs;
    int t = threadIdx.x;
    if (t < NC) h[t] = 0;
    __syncthreads();
    atomicAdd(&h[lab[cb * 256 + t]], 1);
    __syncthreads();
    if (t < NC) bh[cb * NC + t] = h[t];
}

// ---------------- rank/occ (+hist from bhs) ----------------
// grid 64: bx>>5 selects array; out = occ (s) or rank (w). Block 0 also sums hist.
__global__ __launch_bounds__(256) void rankocc_k(const int* __restrict__ s, const int* __restrict__ w,
                                                 const int* __restrict__ bhs, const int* __restrict__ bhw,
                                                 int* __restrict__ occ, int* __restrict__ rank,
                                                 int* __restrict__ hist) {
    __shared__ int ll[256];
    int bx = blockIdx.x, z = bx >> 5, cb = bx & 31;
    const int* lab = z ? w : s;
    const int* bh = z ? bhw : bhs;
    int* out = z ? rank : occ;
    int t = threadIdx.x;
    int j = cb * 256 + t;
    int c = lab[j];
    ll[t] = c;
    __syncthreads();
    int r = 0;
    for (int b = 0; b < cb; b++) r += bh[b * NC + c];
    for (int jj = 0; jj < t; jj++) r += (ll[jj] == c) ? 1 : 0;
    out[j] = r;
    if (bx == 0 && t < 128) {
        int h = 0;
        if (t < NC)
            for (int b = 0; b < 32; b++) h += bhs[b * NC + t];
        hist[t] = h;
    }
}

// ---------------- table[c][occ] = strong index ----------------
__global__ void table_k(const int* __restrict__ s, const int* __restrict__ occ,
                        int* __restrict__ table) {
    int j = blockIdx.x * 256 + threadIdx.x;
    table[s[j] * 8192 + occ[j]] = j;
}

// ---------------- idx[i] = table[w[i]][rank[i] % cnt] ----------------
__global__ void idx_k(const int* __restrict__ w, const int* __restrict__ rank,
                      const int* __restrict__ hist, const int* __restrict__ table,
                      int* __restrict__ idx) {
    int i = blockIdx.x * 256 + threadIdx.x;
    int c = w[i];
    int cc = hist[c];
    idx[i] = (cc > 0) ? table[c * 8192 + (rank[i] % cc)] : 0;
}

// ---------------- fused lpos + l_neg (MFMA) + online-softmax CE ----------------
// grid 256 blocks x 256 thr: 32 q-rows/block; waves 2x2 (wm=row half, wn=col half).
// No staging LDS: A-frags from q (fp32->bf16 regs), B-frags direct from Qt (L2-hot).
__global__ __launch_bounds__(256) void ce_mfma_k(const float* __restrict__ q,
                                                 const float* __restrict__ k,
                                                 const ushort_t* __restrict__ Qt,
                                                 const int* __restrict__ idx,
                                                 const int* __restrict__ w,
                                                 const int* __restrict__ hist,
                                                 float* __restrict__ accum) {
    __shared__ float lpos_lds[32];
    __shared__ float mg[2][32][2];
    int t = threadIdx.x;
    int r0 = blockIdx.x * 32;

    // fused l_pos: row r0+(t>>3), 8 threads x 16 floats each (fp32 exact)
    {
        int r = r0 + (t >> 3);
        int o = (t & 7) * 16;
        const float4* qa = (const float4*)(q + (size_t)r * EMB + o);
        const float4* ka = (const float4*)(k + (size_t)idx[r] * EMB + o);
        float s = 0.f;
#pragma unroll
        for (int p = 0; p < 4; p++) {
            float4 a = qa[p], b = ka[p];
            s += a.x * b.x + a.y * b.y + a.z * b.z + a.w * b.w;
        }
        s += __shfl_xor(s, 1); s += __shfl_xor(s, 2); s += __shfl_xor(s, 4);
        if ((t & 7) == 0) lpos_lds[t >> 3] = s;
    }

    int wv = t >> 6, ln = t & 63;
    int wm = wv >> 1, wn = wv & 1;
    int lane15 = ln & 15, kg = ln >> 4;

    // A-frags direct from q global (each row read by 2 waves)
    short8 afr[4];
#pragma unroll
    for (int ks = 0; ks < 4; ks++) {
        const float4* p = (const float4*)(q + (size_t)(r0 + wm * 16 + lane15) * EMB + ks * 32 + kg * 8);
        float4 a = p[0], b = p[1];
        uint4 pk;
        pk.x = pack2(a.x, a.y); pk.y = pack2(a.z, a.w);
        pk.z = pack2(b.x, b.y); pk.w = pack2(b.z, b.w);
        afr[ks] = __builtin_bit_cast(short8, pk);
    }

    float run_m[4], run_l[4];
#pragma unroll
    for (int j = 0; j < 4; j++) { run_m[j] = -1e30f; run_l[j] = 0.f; }

    for (int nc = 0; nc < 8; nc++) {
        f32x4 acc[4];
#pragma unroll
        for (int nt = 0; nt < 4; nt++) acc[nt] = (f32x4){0.f, 0.f, 0.f, 0.f};
#pragma unroll
        for (int nt = 0; nt < 4; nt++) {
            size_t nrow = (size_t)(nc * 128 + wn * 64 + nt * 16 + lane15) * 128 + kg * 8;
#pragma unroll
            for (int ks = 0; ks < 4; ks++) {
                short8 bf = __builtin_bit_cast(short8, *(const uint4*)(Qt + nrow + ks * 32));
                acc[nt] = __builtin_amdgcn_mfma_f32_16x16x32_bf16(afr[ks], bf, acc[nt], 0, 0, 0);
            }
        }
        // online softmax; lane's rows = wm*16 + kg*4+j, cols covered via shfl over lane15
#pragma unroll
        for (int j = 0; j < 4; j++) {
            float v0 = acc[0][j], v1 = acc[1][j], v2 = acc[2][j], v3 = acc[3][j];
            float mc = fmaxf(fmaxf(v0, v1), fmaxf(v2, v3));
            mc = fmaxf(mc, __shfl_xor(mc, 1));
            mc = fmaxf(mc, __shfl_xor(mc, 2));
            mc = fmaxf(mc, __shfl_xor(mc, 4));
            mc = fmaxf(mc, __shfl_xor(mc, 8));
            float nm = fmaxf(run_m[j], mc);
            float s = __expf(v0 - nm) + __expf(v1 - nm) + __expf(v2 - nm) + __expf(v3 - nm);
            s += __shfl_xor(s, 1);
            s += __shfl_xor(s, 2);
            s += __shfl_xor(s, 4);
            s += __shfl_xor(s, 8);
            run_l[j] = run_l[j] * __expf(run_m[j] - nm) + s;
            run_m[j] = nm;
        }
    }

    if (lane15 == 0) {
#pragma unroll
        for (int j = 0; j < 4; j++) {
            int rl = wm * 16 + kg * 4 + j;
            mg[wn][rl][0] = run_m[j];
            mg[wn][rl][1] = run_l[j];
        }
    }
    __syncthreads();
    if (wv == 0) {
        float cv = 0.f, cc = 0.f;
        if (t < 32) {
            int i = r0 + t;
            float m0 = mg[0][t][0], l0 = mg[0][t][1];
            float m1 = mg[1][t][0], l1 = mg[1][t][1];
            float lp = lpos_lds[t];
            float m = fmaxf(fmaxf(m0, m1), lp);
            float l = l0 * __expf(m0 - m) + l1 * __expf(m1 - m) + __expf(lp - m);
            float ce = -(lp - m - __logf(l));
            if (hist[w[i]] > 0) { cv = ce; cc = 1.f; }
        }
        cv += __shfl_xor(cv, 1);  cc += __shfl_xor(cc, 1);
        cv += __shfl_xor(cv, 2);  cc += __shfl_xor(cc, 2);
        cv += __shfl_xor(cv, 4);  cc += __shfl_xor(cc, 4);
        cv += __shfl_xor(cv, 8);  cc += __shfl_xor(cc, 8);
        cv += __shfl_xor(cv, 16); cc += __shfl_xor(cc, 16);
        cv += __shfl_xor(cv, 32); cc += __shfl_xor(cc, 32);
        if (t == 0) {
            atomicAdd(&accum[0], cv);
            atomicAdd(&accum[1], cc);
        }
    }
}

// ---------------- finalize: loss = sum / max(count,1) -> float32 out ----------------
__global__ void final_k(const float* __restrict__ accum, float* __restrict__ out) {
    if (threadIdx.x == 0 && blockIdx.x == 0) {
        out[0] = accum[0] / fmaxf(accum[1], 1.0f);
    }
}

extern "C" void kernel_launch(void* const* d_in, const int* in_sizes, int n_in,
                              void* d_out, int out_size, void* d_ws, size_t ws_size,
                              hipStream_t stream) {
    const float* feats_strong = (const float*)d_in[0];
    const float* feats_weak   = (const float*)d_in[1];
    const int*   s_lab        = (const int*)d_in[2];
    const int*   w_lab        = (const int*)d_in[3];
    const float* Wq           = (const float*)d_in[4];
    const float* bq           = (const float*)d_in[5];
    const float* Wk           = (const float*)d_in[6];
    const float* bk           = (const float*)d_in[7];
    const float* queue        = (const float*)d_in[8];

    float*    wsf = (float*)d_ws;
    int*      wsi = (int*)d_ws;

    float*    q_g   = wsf + OFF_Q;
    float*    k_g   = wsf + OFF_K;
    int*      table = wsi + OFF_TABLE;
    ushort_t* Wtq   = (ushort_t*)(wsi + OFF_WTQ);
    ushort_t* Wtk   = (ushort_t*)(wsi + OFF_WTK);
    int*      hist  = wsi + OFF_HIST;
    int*      rank  = wsi + OFF_RANK;
    int*      occ   = wsi + OFF_OCC;
    int*      idx   = wsi + OFF_IDX;
    int*      bhs   = wsi + OFF_BHS;
    int*      bhw   = wsi + OFF_BHW;
    float*    accum = wsf + OFF_ACC;
    ushort_t* Qt    = (ushort_t*)(wsi + OFF_QT);

    // 1) bf16 convert/transpose (Wt aliases table region — consumed by enc before table_k)
    cvt_k<<<dim3(128, 3), 256, 0, stream>>>(Wq, Wk, queue, Wtq, Wtk, Qt, accum);

    // 2) both encoder GEMMs, one dispatch, zero-LDS streaming MFMA
    enc_mfma_k<<<256, 256, 0, stream>>>(feats_weak, feats_strong, Wtq, Wtk, bq, bk, q_g, k_g);

    // 3) index chain (4 launches)
    bh_k<<<64, 256, 0, stream>>>(s_lab, w_lab, bhs, bhw);
    rankocc_k<<<64, 256, 0, stream>>>(s_lab, w_lab, bhs, bhw, occ, rank, hist);
    table_k<<<32, 256, 0, stream>>>(s_lab, occ, table);
    idx_k<<<32, 256, 0, stream>>>(w_lab, rank, hist, table, idx);

    // 4) fused lpos + l_neg GEMM + CE, then finalize
    ce_mfma_k<<<256, 256, 0, stream>>>(q_g, k_g, Qt, idx, w_lab, hist, accum);
    final_k<<<1, 64, 0, stream>>>(accum, (float*)d_out);
}

// Round 6
// 189.284 us; speedup vs baseline: 1.6343x; 1.6343x over previous
//
#include <hip/hip_runtime.h>
#include <hip/hip_bf16.h>

// Problem constants (from reference)
#define NW   8192
#define NS   8192
#define FD   1024
#define EMB  128
#define QN   1024
#define NC   80

typedef unsigned short ushort_t;
typedef unsigned int   uint_t;
typedef __attribute__((ext_vector_type(8))) short short8;
typedef __attribute__((ext_vector_type(4))) float f32x4;

// ---------- workspace layout (element offsets, 4B units) ----------
#define OFF_Q      0u           // float [NW*EMB]
#define OFF_K      1048576u     // float [NS*EMB]
#define OFF_TABLE  2097152u     // int   [NC*8192] — aliases Wt (enc runs before table_k)
#define OFF_WTQ    2097152u     // ushort[1024*128] (aliases table)
#define OFF_WTK    2129920u     // ushort[1024*128]
#define OFF_HIST   2752512u     // int   [128]
#define OFF_RANK   2752640u     // int   [NW]
#define OFF_OCC    2760832u     // int   [NS]
#define OFF_IDX    2769024u     // int   [NW]
#define OFF_BHS    2785408u     // int   [32*NC]
#define OFF_BHW    2787968u     // int   [32*NC]
#define OFF_ACC    2790528u     // float [2] : {sum_ce, valid_count}
#define OFF_QT     2790532u     // ushort[1024*128] (Qt: queue^T bf16)

__device__ __forceinline__ ushort_t f2bf(float f) {   // fp32 -> bf16 RNE
    uint_t u = __float_as_uint(f);
    u = (u + 0x7fffu + ((u >> 16) & 1u)) >> 16;
    return (ushort_t)u;
}
__device__ __forceinline__ uint_t pack2(float a, float b) {
    return (uint_t)f2bf(a) | ((uint_t)f2bf(b) << 16);
}

// ---------------- convert+transpose: W -> Wt (tiled bf16), queue -> Qt (bf16) ----------------
// z=0: Wq[1024][128] -> Wtq[kb][n][kk]  (kb=k>>5, kk=k&31)
// z=1: Wk -> Wtk same;  z=2: queue[128][1024] -> Qt[n=1024][k=128]
// Also zeroes accum (block 0,0).
__global__ __launch_bounds__(256) void cvt_k(const float* __restrict__ Wq,
                                             const float* __restrict__ Wk,
                                             const float* __restrict__ queue,
                                             ushort_t* __restrict__ Wtq,
                                             ushort_t* __restrict__ Wtk,
                                             ushort_t* __restrict__ Qt,
                                             float* __restrict__ accum) {
    __shared__ float tile[32][33];
    int z = blockIdx.y, flat = blockIdx.x;
    int t = threadIdx.x;
    if (z == 0 && flat == 0 && t < 2) accum[t] = 0.0f;
    const float* in; ushort_t* out; int r0, c0, C;
    if (z < 2) { in = z ? Wk : Wq; out = z ? Wtk : Wtq; C = 128;
                 r0 = (flat >> 2) * 32; c0 = (flat & 3) * 32; }
    else       { in = queue; out = Qt; C = 1024;
                 r0 = (flat & 3) * 32; c0 = (flat >> 2) * 32; }
    int i = t >> 3, j0 = (t & 7) * 4;
    float4 v = *(const float4*)(in + (size_t)(r0 + i) * C + c0 + j0);
    tile[i][j0] = v.x; tile[i][j0 + 1] = v.y; tile[i][j0 + 2] = v.z; tile[i][j0 + 3] = v.w;
    __syncthreads();
    uint2 pk;
    pk.x = pack2(tile[j0][i], tile[j0 + 1][i]);
    pk.y = pack2(tile[j0 + 2][i], tile[j0 + 3][i]);
    size_t oaddr;
    if (z < 2) oaddr = ((size_t)(r0 >> 5) * 128 + (c0 + i)) * 32 + j0;   // tiled [kb][n][kk]
    else       oaddr = (size_t)(c0 + i) * 128 + (r0 + j0);               // plain [n][k]
    *(uint2*)(out + oaddr) = pk;
}

// ---------------- encoder GEMM (MFMA, zero-LDS, zero-barrier, no dynamic reg-array idx) ----
// grid 512: bx>>8 selects encoder, bx&255 = 32-row tile. 4 waves 2x2:
//   wm = row half (16 rows), wn = col half (64 cols).
// A fp32 read once (HBM), bf16-convert in regs; Wt fragments direct from global (L2-hot).
// Double-buffer via NAMED variables only — constant indices after unroll (round-5 spill fix).
__global__ __launch_bounds__(256) void enc_mfma_k(const float* __restrict__ A0,
                                                  const float* __restrict__ A1,
                                                  const ushort_t* __restrict__ Wt0,
                                                  const ushort_t* __restrict__ Wt1,
                                                  const float* __restrict__ b0_,
                                                  const float* __restrict__ b1_,
                                                  float* __restrict__ out0,
                                                  float* __restrict__ out1) {
    int bx = blockIdx.x;
    int which = bx >> 8;
    int mtile = bx & 255;
    const float*    A    = which ? A1 : A0;
    const ushort_t* Wt   = which ? Wt1 : Wt0;
    const float*    bias = which ? b1_ : b0_;
    float*          out  = which ? out1 : out0;

    int t = threadIdx.x;
    int wv = t >> 6, ln = t & 63;
    int wm = wv >> 1, wn = wv & 1;
    int lane15 = ln & 15, kg = ln >> 4;
    int row0 = mtile * 32 + wm * 16;

    const float* arow = A + (size_t)(row0 + lane15) * FD + kg * 8;
    const ushort_t* wbase = Wt + (wn * 64 + lane15) * 32 + kg * 8;

    f32x4 acc[4];
#pragma unroll
    for (int nt = 0; nt < 4; nt++) acc[nt] = (f32x4){0.f, 0.f, 0.f, 0.f};

    // buffer 0 / buffer 1 — distinct named variables, never runtime-indexed
    float4 a0lo, a0hi, a1lo, a1hi;
    uint4 b0[4], b1[4];

    a0lo = *(const float4*)(arow);
    a0hi = *(const float4*)(arow + 4);
#pragma unroll
    for (int nt = 0; nt < 4; nt++) b0[nt] = *(const uint4*)(wbase + nt * 512);

#pragma unroll 1
    for (int kb = 0; kb < 32; kb += 2) {
        // prefetch kb+1 into buffer 1
        {
            const float* ap = arow + (kb + 1) * 32;
            a1lo = *(const float4*)ap;
            a1hi = *(const float4*)(ap + 4);
            const ushort_t* wp = wbase + (size_t)(kb + 1) * 4096;
#pragma unroll
            for (int nt = 0; nt < 4; nt++) b1[nt] = *(const uint4*)(wp + nt * 512);
        }
        // compute buffer 0
        {
            uint4 pk;
            pk.x = pack2(a0lo.x, a0lo.y); pk.y = pack2(a0lo.z, a0lo.w);
            pk.z = pack2(a0hi.x, a0hi.y); pk.w = pack2(a0hi.z, a0hi.w);
            short8 af = __builtin_bit_cast(short8, pk);
#pragma unroll
            for (int nt = 0; nt < 4; nt++)
                acc[nt] = __builtin_amdgcn_mfma_f32_16x16x32_bf16(
                    af, __builtin_bit_cast(short8, b0[nt]), acc[nt], 0, 0, 0);
        }
        // prefetch kb+2 into buffer 0
        if (kb + 2 < 32) {
            const float* ap = arow + (kb + 2) * 32;
            a0lo = *(const float4*)ap;
            a0hi = *(const float4*)(ap + 4);
            const ushort_t* wp = wbase + (size_t)(kb + 2) * 4096;
#pragma unroll
            for (int nt = 0; nt < 4; nt++) b0[nt] = *(const uint4*)(wp + nt * 512);
        }
        // compute buffer 1
        {
            uint4 pk;
            pk.x = pack2(a1lo.x, a1lo.y); pk.y = pack2(a1lo.z, a1lo.w);
            pk.z = pack2(a1hi.x, a1hi.y); pk.w = pack2(a1hi.z, a1hi.w);
            short8 af = __builtin_bit_cast(short8, pk);
#pragma unroll
            for (int nt = 0; nt < 4; nt++)
                acc[nt] = __builtin_amdgcn_mfma_f32_16x16x32_bf16(
                    af, __builtin_bit_cast(short8, b1[nt]), acc[nt], 0, 0, 0);
        }
    }

    // epilogue: C[row][col], row-within-16 = kg*4+j, col = wn*64 + nt*16 + lane15
#pragma unroll
    for (int nt = 0; nt < 4; nt++) {
        int col = wn * 64 + nt * 16 + lane15;
        float bv = bias[col];
        int rbase = row0 + kg * 4;
#pragma unroll
        for (int j = 0; j < 4; j++)
            out[(size_t)(rbase + j) * EMB + col] = acc[nt][j] + bv;
    }
}

// ---------------- per-block class histograms for both label arrays ----------------
// grid 64: bx>>5 selects array (0=s,1=w), bx&31 = 256-elem chunk.
__global__ __launch_bounds__(256) void bh_k(const int* __restrict__ s, const int* __restrict__ w,
                                            int* __restrict__ bhs, int* __restrict__ bhw) {
    __shared__ int h[NC];
    int bx = blockIdx.x, z = bx >> 5, cb = bx & 31;
    const int* lab = z ? w : s;
    int* bh = z ? bhw : bhs;
    int t = threadIdx.x;
    if (t < NC) h[t] = 0;
    __syncthreads();
    atomicAdd(&h[lab[cb * 256 + t]], 1);
    __syncthreads();
    if (t < NC) bh[cb * NC + t] = h[t];
}

// ---------------- rank/occ (+hist from bhs) ----------------
// grid 64: bx>>5 selects array; out = occ (s) or rank (w). Block 0 also sums hist.
__global__ __launch_bounds__(256) void rankocc_k(const int* __restrict__ s, const int* __restrict__ w,
                                                 const int* __restrict__ bhs, const int* __restrict__ bhw,
                                                 int* __restrict__ occ, int* __restrict__ rank,
                                                 int* __restrict__ hist) {
    __shared__ int ll[256];
    int bx = blockIdx.x, z = bx >> 5, cb = bx & 31;
    const int* lab = z ? w : s;
    const int* bh = z ? bhw : bhs;
    int* out = z ? rank : occ;
    int t = threadIdx.x;
    int j = cb * 256 + t;
    int c = lab[j];
    ll[t] = c;
    __syncthreads();
    int r = 0;
    for (int b = 0; b < cb; b++) r += bh[b * NC + c];
    for (int jj = 0; jj < t; jj++) r += (ll[jj] == c) ? 1 : 0;
    out[j] = r;
    if (bx == 0 && t < 128) {
        int h = 0;
        if (t < NC)
            for (int b = 0; b < 32; b++) h += bhs[b * NC + t];
        hist[t] = h;
    }
}

// ---------------- table[c][occ] = strong index ----------------
__global__ void table_k(const int* __restrict__ s, const int* __restrict__ occ,
                        int* __restrict__ table) {
    int j = blockIdx.x * 256 + threadIdx.x;
    table[s[j] * 8192 + occ[j]] = j;
}

// ---------------- idx[i] = table[w[i]][rank[i] % cnt] ----------------
__global__ void idx_k(const int* __restrict__ w, const int* __restrict__ rank,
                      const int* __restrict__ hist, const int* __restrict__ table,
                      int* __restrict__ idx) {
    int i = blockIdx.x * 256 + threadIdx.x;
    int c = w[i];
    int cc = hist[c];
    idx[i] = (cc > 0) ? table[c * 8192 + (rank[i] % cc)] : 0;
}

// ---------------- fused lpos + l_neg (MFMA) + online-softmax CE ----------------
// grid 256 blocks x 256 thr: 32 q-rows/block; waves 2x2 (wm=row half, wn=col half).
// No staging LDS: A-frags from q (fp32->bf16 regs), B-frags direct from Qt (L2-hot).
__global__ __launch_bounds__(256) void ce_mfma_k(const float* __restrict__ q,
                                                 const float* __restrict__ k,
                                                 const ushort_t* __restrict__ Qt,
                                                 const int* __restrict__ idx,
                                                 const int* __restrict__ w,
                                                 const int* __restrict__ hist,
                                                 float* __restrict__ accum) {
    __shared__ float lpos_lds[32];
    __shared__ float mg[2][32][2];
    int t = threadIdx.x;
    int r0 = blockIdx.x * 32;

    // fused l_pos: row r0+(t>>3), 8 threads x 16 floats each (fp32 exact)
    {
        int r = r0 + (t >> 3);
        int o = (t & 7) * 16;
        const float4* qa = (const float4*)(q + (size_t)r * EMB + o);
        const float4* ka = (const float4*)(k + (size_t)idx[r] * EMB + o);
        float s = 0.f;
#pragma unroll
        for (int p = 0; p < 4; p++) {
            float4 a = qa[p], b = ka[p];
            s += a.x * b.x + a.y * b.y + a.z * b.z + a.w * b.w;
        }
        s += __shfl_xor(s, 1); s += __shfl_xor(s, 2); s += __shfl_xor(s, 4);
        if ((t & 7) == 0) lpos_lds[t >> 3] = s;
    }

    int wv = t >> 6, ln = t & 63;
    int wm = wv >> 1, wn = wv & 1;
    int lane15 = ln & 15, kg = ln >> 4;

    // A-frags direct from q global (each row read by 2 waves)
    short8 afr[4];
#pragma unroll
    for (int ks = 0; ks < 4; ks++) {
        const float4* p = (const float4*)(q + (size_t)(r0 + wm * 16 + lane15) * EMB + ks * 32 + kg * 8);
        float4 a = p[0], b = p[1];
        uint4 pk;
        pk.x = pack2(a.x, a.y); pk.y = pack2(a.z, a.w);
        pk.z = pack2(b.x, b.y); pk.w = pack2(b.z, b.w);
        afr[ks] = __builtin_bit_cast(short8, pk);
    }

    float run_m[4], run_l[4];
#pragma unroll
    for (int j = 0; j < 4; j++) { run_m[j] = -1e30f; run_l[j] = 0.f; }

#pragma unroll 1
    for (int nc = 0; nc < 8; nc++) {
        f32x4 acc[4];
#pragma unroll
        for (int nt = 0; nt < 4; nt++) acc[nt] = (f32x4){0.f, 0.f, 0.f, 0.f};
#pragma unroll
        for (int nt = 0; nt < 4; nt++) {
            size_t nrow = (size_t)(nc * 128 + wn * 64 + nt * 16 + lane15) * 128 + kg * 8;
#pragma unroll
            for (int ks = 0; ks < 4; ks++) {
                short8 bf = __builtin_bit_cast(short8, *(const uint4*)(Qt + nrow + ks * 32));
                acc[nt] = __builtin_amdgcn_mfma_f32_16x16x32_bf16(afr[ks], bf, acc[nt], 0, 0, 0);
            }
        }
        // online softmax; lane's rows = wm*16 + kg*4+j, cols covered via shfl over lane15
#pragma unroll
        for (int j = 0; j < 4; j++) {
            float v0 = acc[0][j], v1 = acc[1][j], v2 = acc[2][j], v3 = acc[3][j];
            float mc = fmaxf(fmaxf(v0, v1), fmaxf(v2, v3));
            mc = fmaxf(mc, __shfl_xor(mc, 1));
            mc = fmaxf(mc, __shfl_xor(mc, 2));
            mc = fmaxf(mc, __shfl_xor(mc, 4));
            mc = fmaxf(mc, __shfl_xor(mc, 8));
            float nm = fmaxf(run_m[j], mc);
            float s = __expf(v0 - nm) + __expf(v1 - nm) + __expf(v2 - nm) + __expf(v3 - nm);
            s += __shfl_xor(s, 1);
            s += __shfl_xor(s, 2);
            s += __shfl_xor(s, 4);
            s += __shfl_xor(s, 8);
            run_l[j] = run_l[j] * __expf(run_m[j] - nm) + s;
            run_m[j] = nm;
        }
    }

    if (lane15 == 0) {
#pragma unroll
        for (int j = 0; j < 4; j++) {
            int rl = wm * 16 + kg * 4 + j;
            mg[wn][rl][0] = run_m[j];
            mg[wn][rl][1] = run_l[j];
        }
    }
    __syncthreads();
    if (wv == 0) {
        float cv = 0.f, cc = 0.f;
        if (t < 32) {
            int i = r0 + t;
            float m0 = mg[0][t][0], l0 = mg[0][t][1];
            float m1 = mg[1][t][0], l1 = mg[1][t][1];
            float lp = lpos_lds[t];
            float m = fmaxf(fmaxf(m0, m1), lp);
            float l = l0 * __expf(m0 - m) + l1 * __expf(m1 - m) + __expf(lp - m);
            float ce = -(lp - m - __logf(l));
            if (hist[w[i]] > 0) { cv = ce; cc = 1.f; }
        }
        cv += __shfl_xor(cv, 1);  cc += __shfl_xor(cc, 1);
        cv += __shfl_xor(cv, 2);  cc += __shfl_xor(cc, 2);
        cv += __shfl_xor(cv, 4);  cc += __shfl_xor(cc, 4);
        cv += __shfl_xor(cv, 8);  cc += __shfl_xor(cc, 8);
        cv += __shfl_xor(cv, 16); cc += __shfl_xor(cc, 16);
        cv += __shfl_xor(cv, 32); cc += __shfl_xor(cc, 32);
        if (t == 0) {
            atomicAdd(&accum[0], cv);
            atomicAdd(&accum[1], cc);
        }
    }
}

// ---------------- finalize: loss = sum / max(count,1) -> float32 out ----------------
__global__ void final_k(const float* __restrict__ accum, float* __restrict__ out) {
    if (threadIdx.x == 0 && blockIdx.x == 0) {
        out[0] = accum[0] / fmaxf(accum[1], 1.0f);
    }
}

extern "C" void kernel_launch(void* const* d_in, const int* in_sizes, int n_in,
                              void* d_out, int out_size, void* d_ws, size_t ws_size,
                              hipStream_t stream) {
    const float* feats_strong = (const float*)d_in[0];
    const float* feats_weak   = (const float*)d_in[1];
    const int*   s_lab        = (const int*)d_in[2];
    const int*   w_lab        = (const int*)d_in[3];
    const float* Wq           = (const float*)d_in[4];
    const float* bq           = (const float*)d_in[5];
    const float* Wk           = (const float*)d_in[6];
    const float* bk           = (const float*)d_in[7];
    const float* queue        = (const float*)d_in[8];

    float*    wsf = (float*)d_ws;
    int*      wsi = (int*)d_ws;

    float*    q_g   = wsf + OFF_Q;
    float*    k_g   = wsf + OFF_K;
    int*      table = wsi + OFF_TABLE;
    ushort_t* Wtq   = (ushort_t*)(wsi + OFF_WTQ);
    ushort_t* Wtk   = (ushort_t*)(wsi + OFF_WTK);
    int*      hist  = wsi + OFF_HIST;
    int*      rank  = wsi + OFF_RANK;
    int*      occ   = wsi + OFF_OCC;
    int*      idx   = wsi + OFF_IDX;
    int*      bhs   = wsi + OFF_BHS;
    int*      bhw   = wsi + OFF_BHW;
    float*    accum = wsf + OFF_ACC;
    ushort_t* Qt    = (ushort_t*)(wsi + OFF_QT);

    // 1) bf16 convert/transpose (Wt aliases table region — consumed by enc before table_k)
    cvt_k<<<dim3(128, 3), 256, 0, stream>>>(Wq, Wk, queue, Wtq, Wtk, Qt, accum);

    // 2) both encoder GEMMs, one dispatch, zero-LDS streaming MFMA (512 blocks, 2/CU)
    enc_mfma_k<<<512, 256, 0, stream>>>(feats_weak, feats_strong, Wtq, Wtk, bq, bk, q_g, k_g);

    // 3) index chain (4 launches)
    bh_k<<<64, 256, 0, stream>>>(s_lab, w_lab, bhs, bhw);
    rankocc_k<<<64, 256, 0, stream>>>(s_lab, w_lab, bhs, bhw, occ, rank, hist);
    table_k<<<32, 256, 0, stream>>>(s_lab, occ, table);
    idx_k<<<32, 256, 0, stream>>>(w_lab, rank, hist, table, idx);

    // 4) fused lpos + l_neg GEMM + CE, then finalize
    ce_mfma_k<<<256, 256, 0, stream>>>(q_g, k_g, Qt, idx, w_lab, hist, accum);
    final_k<<<1, 64, 0, stream>>>(accum, (float*)d_out);
}